// Round 1
// baseline (2571.090 us; speedup 1.0000x reference)
//
#include <hip/hip_runtime.h>
#include <cstddef>

// ============================================================================
// VLSTM: masked LSTM scan. T=20 steps, N=32768 independent cells, D_H=128.
// Strategy: persistent per-block node tile (M=32 nodes). h state lives in LDS
// (transposed [k][node] so the gate GEMM reads it as the A operand), c state
// lives in the owning threads' registers. Weights are pre-packed into d_ws
// with [unit][gate] column interleave so each thread's 8 gate-weights per k
// are two contiguous float4 loads, and b_ih+b_hh pre-summed.
// Compute-bound on fp32 VALU (~1.3e11 FLOP, no fp32 MFMA on CDNA4).
// ============================================================================

namespace {
constexpr int T_STEPS = 20;
constexpr int NN      = 32768;
constexpr int D_EMB   = 64;
constexpr int D_H     = 128;
constexpr int D_OUT   = 5;
constexpr int KTOT    = 192;   // D_EMB + D_H
constexpr int G4      = 512;   // 4 * D_H
constexpr int M_TILE  = 32;    // nodes per block
constexpr int BLOCK   = 256;
constexpr int ASTR    = 36;    // LDS row stride (floats): 32 + 4 pad, keeps 16B
                               // alignment and rotates banks by 4 per row
}

// ----------------------------------------------------------------------------
// Pre-pack weights: W_pack[k][j], j = unit*4 + gate, orig col = gate*128+unit.
// k<64 -> W_ih row k ; k>=64 -> W_hh row k-64.  b_pack[j] = b_ih+b_hh.
// ----------------------------------------------------------------------------
__global__ void prepack_kernel(const float* __restrict__ W_ih,
                               const float* __restrict__ b_ih,
                               const float* __restrict__ W_hh,
                               const float* __restrict__ b_hh,
                               float* __restrict__ W_pack,
                               float* __restrict__ b_pack) {
    int idx = blockIdx.x * blockDim.x + threadIdx.x;
    if (idx < KTOT * G4) {
        int k = idx / G4, j = idx % G4;
        int unit = j >> 2, gate = j & 3;
        int col = gate * D_H + unit;
        W_pack[idx] = (k < D_EMB) ? W_ih[k * G4 + col]
                                  : W_hh[(k - D_EMB) * G4 + col];
    }
    if (idx < G4) {
        int unit = idx >> 2, gate = idx & 3;
        int col = gate * D_H + unit;
        b_pack[idx] = b_ih[col] + b_hh[col];
    }
}

__device__ __forceinline__ float sigf(float x) {
    float e = __expf(-x);
    return __fdividef(1.0f, 1.0f + e);
}
__device__ __forceinline__ float tanh_fast(float x) {
    x = fminf(15.0f, fmaxf(-15.0f, x));          // avoid inf/inf
    float e = __expf(2.0f * x);
    return __fdividef(e - 1.0f, e + 1.0f);
}

// ----------------------------------------------------------------------------
// Main persistent kernel. Grid = NN/M_TILE = 1024 blocks of 256 threads.
// Thread map: nb = tid&7 -> 4 nodes (4*nb..4*nb+3); ub = tid>>3 in [0,32).
// Gate GEMM runs in 2 unit-passes of 64 units; thread owns units 64p+2ub+{0,1}.
// ----------------------------------------------------------------------------
__global__ __launch_bounds__(BLOCK, 4) void vlstm_kernel(
    const float* __restrict__ nodes,   // [T][N][2]
    const int*   __restrict__ mask,    // [T][N] (bool stored as int32)
    const float* __restrict__ h0,      // [N][128]
    const float* __restrict__ c0,      // [N][128]
    const float* __restrict__ W_embed, // [2][64]
    const float* __restrict__ b_embed, // [64]
    const float* __restrict__ W_out,   // [128][5]
    const float* __restrict__ b_out,   // [5]
    const float* __restrict__ W_pack,  // [192][512] packed
    const float* __restrict__ b_pack,  // [512] packed
    float* __restrict__ out)           // [T][N][5] ++ h_fin[N][128] ++ c_fin
{
    constexpr size_t OUT_OFF_H = (size_t)T_STEPS * NN * D_OUT;
    constexpr size_t OUT_OFF_C = OUT_OFF_H + (size_t)NN * D_H;

    __shared__ __align__(16) float A[KTOT * ASTR];   // rows 0..63 emb, 64..191 h

    const int tid    = threadIdx.x;
    const int nb     = tid & 7;    // node group (4 nodes)
    const int ub     = tid >> 3;   // unit group in [0,32)
    const int n_base = blockIdx.x * M_TILE;

    // ---- init: h0 -> LDS (coalesced global read), c0 -> owner registers ----
    for (int idx = tid; idx < M_TILE * D_H; idx += BLOCK) {
        int n = idx >> 7, u = idx & 127;
        A[(D_EMB + u) * ASTR + n] = h0[(size_t)(n_base + n) * D_H + u];
    }
    float c[4][2][2];      // [node][pass][unit-in-pair]
    #pragma unroll
    for (int n = 0; n < 4; n++)
        #pragma unroll
        for (int p = 0; p < 2; p++) {
            const float* src = c0 + (size_t)(n_base + 4 * nb + n) * D_H + 64 * p + 2 * ub;
            c[n][p][0] = src[0];
            c[n][p][1] = src[1];
        }
    __syncthreads();

    for (int t = 0; t < T_STEPS; t++) {
        // ---- emb phase: emb = relu(x @ W_embed + b_embed), write A rows 0..63
        {
            int node = tid >> 3, eb = tid & 7;
            const float* xp = nodes + ((size_t)t * NN + n_base + node) * 2;
            float x0 = xp[0], x1 = xp[1];
            #pragma unroll
            for (int j = 0; j < 8; j++) {
                int e = eb + 8 * j;
                float v = fmaf(x0, W_embed[e], fmaf(x1, W_embed[D_EMB + e], b_embed[e]));
                A[e * ASTR + node] = fmaxf(v, 0.0f);
            }
        }
        __syncthreads();   // barrier A: emb (and h) visible for GEMM

        int mloc[4];
        #pragma unroll
        for (int n = 0; n < 4; n++)
            mloc[n] = mask[(size_t)t * NN + n_base + 4 * nb + n];

        float hn[4][2][2];

        // ---- gate GEMM: 2 passes over units, K-loop over 192 ----
        #pragma unroll
        for (int p = 0; p < 2; p++) {
            float acc[4][2][4];   // [node][unit][gate i,f,g,o]
            {
                const float* bp = b_pack + (64 * p + 2 * ub) * 4;
                #pragma unroll
                for (int g = 0; g < 4; g++) {
                    float bb0 = bp[g], bb1 = bp[4 + g];
                    #pragma unroll
                    for (int n = 0; n < 4; n++) { acc[n][0][g] = bb0; acc[n][1][g] = bb1; }
                }
            }
            const float* ap = A + 4 * nb;
            const float* wp = W_pack + (size_t)(64 * p + 2 * ub) * 4;
            #pragma unroll 2
            for (int k = 0; k < KTOT; k++) {
                float4 a  = *(const float4*)(ap);
                float4 w0 = *(const float4*)(wp);
                float4 w1 = *(const float4*)(wp + 4);
                ap += ASTR; wp += G4;
                float av[4] = {a.x, a.y, a.z, a.w};
                float wv0[4] = {w0.x, w0.y, w0.z, w0.w};
                float wv1[4] = {w1.x, w1.y, w1.z, w1.w};
                #pragma unroll
                for (int n = 0; n < 4; n++) {
                    #pragma unroll
                    for (int g = 0; g < 4; g++) {
                        acc[n][0][g] = fmaf(av[n], wv0[g], acc[n][0][g]);
                        acc[n][1][g] = fmaf(av[n], wv1[g], acc[n][1][g]);
                    }
                }
            }
            // ---- activations + c update (thread-local; h write deferred) ----
            #pragma unroll
            for (int n = 0; n < 4; n++)
                #pragma unroll
                for (int uu = 0; uu < 2; uu++) {
                    float gi = sigf(acc[n][uu][0]);
                    float gf = sigf(acc[n][uu][1]);
                    float gg = tanh_fast(acc[n][uu][2]);
                    float go = sigf(acc[n][uu][3]);
                    float cn = fmaf(gf, c[n][p][uu], gi * gg);
                    float hv = go * tanh_fast(cn);
                    if (mloc[n]) c[n][p][uu] = cn;
                    hn[n][p][uu] = hv;
                }
        }
        __syncthreads();   // barrier B: all K-loop reads of A done

        // ---- write h_new into LDS where present ----
        #pragma unroll
        for (int n = 0; n < 4; n++)
            if (mloc[n]) {
                #pragma unroll
                for (int p = 0; p < 2; p++) {
                    #pragma unroll
                    for (int uu = 0; uu < 2; uu++) {
                        int ug = 64 * p + 2 * ub + uu;
                        A[(D_EMB + ug) * ASTR + 4 * nb + n] = hn[n][p][uu];
                    }
                }
            }
        __syncthreads();   // barrier C: updated h visible

        // ---- output phase: out = mask ? h_new @ W_out + b_out : 0 ----
        for (int idx = tid; idx < M_TILE * D_OUT; idx += BLOCK) {
            int node = idx / D_OUT, d = idx % D_OUT;
            float s = 0.0f;
            if (mask[(size_t)t * NN + n_base + node]) {
                s = b_out[d];
                for (int u = 0; u < D_H; u++)
                    s = fmaf(A[(D_EMB + u) * ASTR + node], W_out[u * D_OUT + d], s);
            }
            out[((size_t)t * NN + n_base + node) * D_OUT + d] = s;
        }
        // no barrier needed: next emb phase writes rows 0..63; out reads 64..191
    }

    // ---- final state stores ----
    for (int idx = tid; idx < M_TILE * D_H; idx += BLOCK) {
        int n = idx >> 7, u = idx & 127;
        out[OUT_OFF_H + (size_t)(n_base + n) * D_H + u] = A[(D_EMB + u) * ASTR + n];
    }
    #pragma unroll
    for (int n = 0; n < 4; n++)
        #pragma unroll
        for (int p = 0; p < 2; p++) {
            size_t base = OUT_OFF_C + (size_t)(n_base + 4 * nb + n) * D_H + 64 * p + 2 * ub;
            out[base]     = c[n][p][0];
            out[base + 1] = c[n][p][1];
        }
}

extern "C" void kernel_launch(void* const* d_in, const int* in_sizes, int n_in,
                              void* d_out, int out_size, void* d_ws, size_t ws_size,
                              hipStream_t stream) {
    const float* nodes   = (const float*)d_in[0];
    const int*   mask    = (const int*)  d_in[1];
    const float* h0      = (const float*)d_in[2];
    const float* c0      = (const float*)d_in[3];
    const float* W_embed = (const float*)d_in[4];
    const float* b_embed = (const float*)d_in[5];
    const float* W_ih    = (const float*)d_in[6];
    const float* b_ih    = (const float*)d_in[7];
    const float* W_hh    = (const float*)d_in[8];
    const float* b_hh    = (const float*)d_in[9];
    const float* W_out   = (const float*)d_in[10];
    const float* b_out   = (const float*)d_in[11];
    float* out = (float*)d_out;

    float* W_pack = (float*)d_ws;              // 192*512 floats = 384 KB
    float* b_pack = W_pack + KTOT * G4;        // 512 floats

    prepack_kernel<<<(KTOT * G4 + 255) / 256, 256, 0, stream>>>(
        W_ih, b_ih, W_hh, b_hh, W_pack, b_pack);

    vlstm_kernel<<<NN / M_TILE, BLOCK, 0, stream>>>(
        nodes, mask, h0, c0, W_embed, b_embed, W_out, b_out, W_pack, b_pack, out);
}

// Round 2
// 495.150 us; speedup vs baseline: 5.1925x; 5.1925x over previous
//
#include <hip/hip_runtime.h>
#include <cstddef>

// ============================================================================
// VLSTM via bf16 MFMA. 512 blocks x 512 threads (8 waves), 64 nodes/block,
// persistent over T=20 steps.
//  - A = [emb(64) | h(128)] per block, bf16, stored in LDS in MFMA A-fragment
//    order: element (m,k) -> A[(( (m>>4)*6 + (k>>5) )*64 + ((k>>3&3)*16 + (m&15)))*8 + (k&7)]
//    so a wave's ds_read_b128 at lane L yields A[m=rt*16+(L&15)][k=kb*32+(L>>4)*8+j].
//  - Weights: all 192x512 pre-packed as bf16 B-fragments in d_ws; each wave
//    loads its 24 fragments (4 gates x 6 k-blocks, 96 VGPR) ONCE and keeps
//    them in registers for the whole kernel -> no weight traffic in the loop.
//  - Wave w owns units [16w,16w+16). Col-tile g = gate g of those units
//    (original gate-major columns g*128+u) -> after MFMA, lane L holds
//    i,f,g,o of (node m = rt*16+(L>>4)*4+r, unit u = 16w+(L&15)) in
//    acc[rt][0..3][r]: activations are lane-local, zero cross-lane ops.
//  - c state: fp32 in registers of the owning lane. h state: bf16 in LDS.
// ============================================================================

typedef __attribute__((ext_vector_type(8))) short  s16x8;   // 8 x bf16
typedef __attribute__((ext_vector_type(4))) float  f32x4;

namespace {
constexpr int T_STEPS = 20;
constexpr int NN      = 32768;
constexpr int D_EMB   = 64;
constexpr int D_H     = 128;
constexpr int D_OUT   = 5;
constexpr int G4      = 512;
constexpr int MT      = 64;            // nodes per block
constexpr int BLOCK   = 512;           // 8 waves
constexpr int GRID    = NN / MT;       // 512
constexpr int WP_ELEMS = 8 * 4 * 6 * 64 * 8;   // 98304 bf16 fragments
constexpr size_t OFF_H = (size_t)T_STEPS * NN * D_OUT;
constexpr size_t OFF_C = OFF_H + (size_t)NN * D_H;
}

__device__ __forceinline__ unsigned short f2bf(float x) {
    unsigned u = __float_as_uint(x);
    u = (u + 0x7FFFu + ((u >> 16) & 1u)) >> 16;     // RNE
    return (unsigned short)u;
}
__device__ __forceinline__ float bf2f(unsigned short h) {
    return __uint_as_float(((unsigned)h) << 16);
}
__device__ __forceinline__ float sigf(float x) {
    return __fdividef(1.0f, 1.0f + __expf(-x));
}
__device__ __forceinline__ float tanhf_fast(float x) {
    // 1 - 2/(1+e^{2x}); inf-safe at both ends
    return 1.0f - __fdividef(2.0f, 1.0f + __expf(2.0f * x));
}

// ----------------------------------------------------------------------------
// Pre-pack: Wp[w][g][kb][lane][j] (bf16) = Wcat[k][col],
//   k = kb*32 + (lane>>4)*8 + j, col = g*128 + w*16 + (lane&15),
//   Wcat = [W_ih ; W_hh].  b_sum[col] = b_ih[col] + b_hh[col].
// ----------------------------------------------------------------------------
__global__ void prepack_kernel(const float* __restrict__ W_ih,
                               const float* __restrict__ b_ih,
                               const float* __restrict__ W_hh,
                               const float* __restrict__ b_hh,
                               unsigned short* __restrict__ Wp,
                               float* __restrict__ b_sum) {
    int idx = blockIdx.x * blockDim.x + threadIdx.x;
    if (idx < WP_ELEMS) {
        int j    = idx & 7;
        int L    = (idx >> 3) & 63;
        int rest = idx >> 9;            // (w*4+g)*6 + kb
        int kb   = rest % 6;
        int gw   = rest / 6;
        int g    = gw & 3, w = gw >> 2;
        int k    = kb * 32 + (L >> 4) * 8 + j;
        int col  = g * D_H + w * 16 + (L & 15);
        float v  = (k < D_EMB) ? W_ih[k * G4 + col] : W_hh[(k - D_EMB) * G4 + col];
        Wp[idx] = f2bf(v);
    }
    if (idx < G4) b_sum[idx] = b_ih[idx] + b_hh[idx];
}

// ----------------------------------------------------------------------------
__global__ __launch_bounds__(BLOCK, 2) void vlstm_kernel(
    const float* __restrict__ nodes,   // [T][N][2]
    const int*   __restrict__ mask,    // [T][N]
    const float* __restrict__ h0,      // [N][128]
    const float* __restrict__ c0,      // [N][128]
    const float* __restrict__ W_embed, // [2][64]
    const float* __restrict__ b_embed, // [64]
    const float* __restrict__ W_out,   // [128][5]
    const float* __restrict__ b_out,   // [5]
    const unsigned short* __restrict__ Wp,
    const float* __restrict__ b_sum,
    float* __restrict__ out)
{
    __shared__ __align__(16) unsigned short A[24 * 64 * 8];   // 24 KB frag-order
    __shared__ __align__(16) float WoutT[D_OUT * D_H];        // [d][u]
    __shared__ float We_s[2 * D_EMB];
    __shared__ float be_s[D_EMB];
    __shared__ int   msk_s[MT];

    const int tid  = threadIdx.x;
    const int wave = tid >> 6;
    const int L    = tid & 63;
    const int quad = L >> 4;
    const int l15  = L & 15;
    const int n_base = blockIdx.x * MT;

    // ---- B fragments (weights) -> registers, once ----
    s16x8 Bf[4][6];
    #pragma unroll
    for (int g = 0; g < 4; g++)
        #pragma unroll
        for (int kb = 0; kb < 6; kb++)
            Bf[g][kb] = *(const s16x8*)(Wp + ((((wave * 4 + g) * 6 + kb) * 64) + L) * 8);

    float bias[4];
    #pragma unroll
    for (int g = 0; g < 4; g++) bias[g] = b_sum[g * D_H + wave * 16 + l15];

    // ---- one-time LDS staging ----
    for (int i = tid; i < D_OUT * D_H; i += BLOCK) {
        int d = i >> 7, u = i & 127;
        WoutT[i] = W_out[u * D_OUT + d];           // WoutT[d*128+u]
    }
    for (int i = tid; i < 3 * D_EMB; i += BLOCK) {
        if (i < 2 * D_EMB) We_s[i] = W_embed[i];
        else               be_s[i - 2 * D_EMB] = b_embed[i - 2 * D_EMB];
    }
    for (int i = tid; i < MT * D_H; i += BLOCK) {   // h0 -> A rows 64..191
        int node = i >> 7, u = i & 127;
        int k = D_EMB + u;
        int idx = (((node >> 4) * 6 + (k >> 5)) * 64 + ((k >> 3) & 3) * 16 + (node & 15)) * 8 + (k & 7);
        A[idx] = f2bf(h0[(size_t)(n_base + node) * D_H + u]);
    }
    const int u_lane = wave * 16 + l15;
    float c[4][4];                                  // [rt][r]
    #pragma unroll
    for (int rt = 0; rt < 4; rt++)
        #pragma unroll
        for (int r = 0; r < 4; r++) {
            int m = rt * 16 + quad * 4 + r;
            c[rt][r] = c0[(size_t)(n_base + m) * D_H + u_lane];
        }
    __syncthreads();

    const int node_e = tid >> 3;    // emb-phase node
    const int eb     = tid & 7;     // emb-phase e-block (8 e's)

    for (int t = 0; t < T_STEPS; t++) {
        // ---- emb = relu(x @ W_embed + b) -> A rows 0..63 ; stage mask ----
        {
            const float* xp = nodes + ((size_t)t * NN + n_base + node_e) * 2;
            float x0 = xp[0], x1 = xp[1];
            s16x8 ev;
            #pragma unroll
            for (int j = 0; j < 8; j++) {
                int e = eb * 8 + j;
                float v = fmaf(x0, We_s[e], fmaf(x1, We_s[D_EMB + e], be_s[e]));
                ev[j] = (short)f2bf(fmaxf(v, 0.0f));
            }
            int idx = (((node_e >> 4) * 6 + (eb >> 2)) * 64 + (eb & 3) * 16 + (node_e & 15)) * 8;
            *(s16x8*)(A + idx) = ev;               // one ds_write_b128
            if (tid < MT) msk_s[tid] = mask[(size_t)t * NN + n_base + tid];
        }
        __syncthreads();   // B1: A + mask ready

        // ---- gate GEMM: 24 ds_read_b128 + 96 MFMA per wave ----
        f32x4 acc[4][4];   // [rt][gate]
        #pragma unroll
        for (int rt = 0; rt < 4; rt++)
            #pragma unroll
            for (int g = 0; g < 4; g++)
                acc[rt][g] = (f32x4){bias[g], bias[g], bias[g], bias[g]};
        #pragma unroll
        for (int kb = 0; kb < 6; kb++) {
            #pragma unroll
            for (int rt = 0; rt < 4; rt++) {
                s16x8 af = *(const s16x8*)(A + ((rt * 6 + kb) * 64 + L) * 8);
                #pragma unroll
                for (int g = 0; g < 4; g++)
                    acc[rt][g] = __builtin_amdgcn_mfma_f32_16x16x32_bf16(
                        af, Bf[g][kb], acc[rt][g], 0, 0, 0);
            }
        }

        // ---- activations: lane-local (gates live in acc[rt][0..3][r]) ----
        unsigned mbits = 0;
        unsigned short hbf[4][4];
        #pragma unroll
        for (int rt = 0; rt < 4; rt++)
            #pragma unroll
            for (int r = 0; r < 4; r++) {
                int m = rt * 16 + quad * 4 + r;
                int mval = msk_s[m];
                float gi = sigf(acc[rt][0][r]);
                float gf = sigf(acc[rt][1][r]);
                float gg = tanhf_fast(acc[rt][2][r]);
                float go = sigf(acc[rt][3][r]);
                float cn = fmaf(gf, c[rt][r], gi * gg);
                float hv = go * tanhf_fast(cn);
                if (mval) { c[rt][r] = cn; mbits |= 1u << (rt * 4 + r); }
                hbf[rt][r] = f2bf(hv);
            }
        __syncthreads();   // B2: every wave done reading A

        // ---- write h_new (masked) into A rows 64..191 ----
        {
            int kb_u = 2 + (u_lane >> 5);
            int fl   = ((u_lane >> 3) & 3) * 16 + quad * 4;
            int j_u  = u_lane & 7;
            #pragma unroll
            for (int rt = 0; rt < 4; rt++)
                #pragma unroll
                for (int r = 0; r < 4; r++)
                    if ((mbits >> (rt * 4 + r)) & 1u)
                        A[((rt * 6 + kb_u) * 64 + fl + r) * 8 + j_u] = hbf[rt][r];
        }
        __syncthreads();   // B3: new h visible

        // ---- out = mask ? h @ W_out + b_out : 0 ----
        if (tid < MT * D_OUT) {
            int node = tid / D_OUT, d = tid - node * D_OUT;
            int nrt = node >> 4, n15 = node & 15;
            float p0 = 0.0f, p1 = 0.0f;
            int mv = msk_s[node];
            if (mv) {
                #pragma unroll
                for (int s = 0; s < 16; s++) {
                    int idx = ((nrt * 6 + 2 + (s >> 2)) * 64 + (s & 3) * 16 + n15) * 8;
                    s16x8 hf = *(const s16x8*)(A + idx);
                    const float* wrow = &WoutT[d * D_H + s * 8];
                    #pragma unroll
                    for (int j = 0; j < 8; j++) {
                        float hv = bf2f((unsigned short)hf[j]);
                        if (j & 1) p1 = fmaf(hv, wrow[j], p1);
                        else       p0 = fmaf(hv, wrow[j], p0);
                    }
                }
            }
            out[((size_t)t * NN + n_base + node) * D_OUT + d] =
                mv ? (p0 + p1 + b_out[d]) : 0.0f;
        }
        __syncthreads();   // B4: protect msk_s / A for next iteration
    }

    // ---- epilogue: h_fin (from A, bf16->f32), c_fin (exact fp32 regs) ----
    for (int i = tid; i < MT * D_H; i += BLOCK) {
        int node = i >> 7, u = i & 127;
        int k = D_EMB + u;
        int idx = (((node >> 4) * 6 + (k >> 5)) * 64 + ((k >> 3) & 3) * 16 + (node & 15)) * 8 + (k & 7);
        out[OFF_H + (size_t)(n_base + node) * D_H + u] = bf2f(A[idx]);
    }
    #pragma unroll
    for (int rt = 0; rt < 4; rt++)
        #pragma unroll
        for (int r = 0; r < 4; r++) {
            int m = rt * 16 + quad * 4 + r;
            out[OFF_C + (size_t)(n_base + m) * D_H + u_lane] = c[rt][r];
        }
}

extern "C" void kernel_launch(void* const* d_in, const int* in_sizes, int n_in,
                              void* d_out, int out_size, void* d_ws, size_t ws_size,
                              hipStream_t stream) {
    const float* nodes   = (const float*)d_in[0];
    const int*   mask    = (const int*)  d_in[1];
    const float* h0      = (const float*)d_in[2];
    const float* c0      = (const float*)d_in[3];
    const float* W_embed = (const float*)d_in[4];
    const float* b_embed = (const float*)d_in[5];
    const float* W_ih    = (const float*)d_in[6];
    const float* b_ih    = (const float*)d_in[7];
    const float* W_hh    = (const float*)d_in[8];
    const float* b_hh    = (const float*)d_in[9];
    const float* W_out   = (const float*)d_in[10];
    const float* b_out   = (const float*)d_in[11];
    float* out = (float*)d_out;

    unsigned short* Wp    = (unsigned short*)d_ws;           // 192 KB
    float*          b_sum = (float*)((char*)d_ws + WP_ELEMS * sizeof(unsigned short));

    prepack_kernel<<<(WP_ELEMS + 255) / 256, 256, 0, stream>>>(
        W_ih, b_ih, W_hh, b_hh, Wp, b_sum);

    vlstm_kernel<<<GRID, BLOCK, 0, stream>>>(
        nodes, mask, h0, c0, W_embed, b_embed, W_out, b_out, Wp, b_sum, out);
}